// Round 9
// baseline (3114.531 us; speedup 1.0000x reference)
//
#include <hip/hip_runtime.h>

// DSTP-RNN fused forward v7: 256-thread WG (4 waves), one batch element per WG,
// 512 WGs -> 2 WG/CU (proven co-resident at VGPR<=128, round 2).
// vs v1: barriers 12->7 per enc+dec step-pair, preact->gates fused in-register
// (permuted row mapping + quad shfl), ping-pong state, img prefetch,
// per-wave own-chunk beta (no softmax broadcast barrier), hoisted hhdot.

#define TSTEPS 128

// LDS float offsets (total 20080 floats = 80320 B; 2 WG/CU: 160640 <= 163840)
#define ENC    0        // [128][64] encoded h
#define UENC   8192     // [64][136] Uenc transposed (2-way reads, ~free)
#define UE     16896    // 1024: Ue_w (encoder) ; decoder const pool overlays
#define EBIAS  17920    // 256: enc bias sums (ebih+ebhh), permuted-row indexed
#define CTLT   18176    // [8][68] conv tile (enc) ; DC_YH (dec, 128) overlays
#define XVE    18720    // [128][2] (x_j, ve_j) / (x1_j, vd_j)
#define HSB    18976    // [2][144]: ping-pong state, 4 chunks of 32 @ stride 36
#define GBUF   19264    // 256: dec c_t partials
#define RED    19520    // 256: enc e-partials ; dec BETA(128)+CTV(64)+TYP(64)
#define IMG    19776    // [2][88]: double-buffered 9x9 image
#define LBUF   19952    // 128: dec l
#define SMEMF  20080

// decoder const overlays (UE region, loaded after encoder)
#define DC_WT    (UE + 64)    // 65
#define DC_DWIH  (UE + 192)   // 256
#define DC_DBIAS (UE + 448)   // 256
#define DC_WDB   (UE + 704)   // 64
#define DC_WYB   (UE + 768)   // 64
#define DC_VY    (UE + 832)   // 64
#define DC_SC    (UE + 896)   // wtb, vyb
#define DC_YH    CTLT
#define BETA     RED          // 128 (dec)
#define CTV      (RED + 128)  // 64 (written only at t==127)
#define TYP      (RED + 192)  // 64 (head)

__device__ __forceinline__ float rcpf(float x) { return __builtin_amdgcn_rcpf(x); }
__device__ __forceinline__ float fsigm(float x) { return rcpf(1.0f + __expf(-x)); }
__device__ __forceinline__ float ftanh(float x) { return 1.0f - 2.0f * rcpf(1.0f + __expf(2.0f * x)); }

#define FMA4(d_, p_, q_) \
    d_ = fmaf((p_).x, (q_).x, d_); d_ = fmaf((p_).y, (q_).y, d_); \
    d_ = fmaf((p_).z, (q_).z, d_); d_ = fmaf((p_).w, (q_).w, d_);

__global__ __launch_bounds__(256, 4) void dstp_kernel(
    const float* __restrict__ Xh,   const float* __restrict__ yh,
    const float* __restrict__ convw,const float* __restrict__ convb,
    const float* __restrict__ Wew,  const float* __restrict__ Web,
    const float* __restrict__ Uew,  const float* __restrict__ vew,
    const float* __restrict__ eWih, const float* __restrict__ eWhh,
    const float* __restrict__ ebih, const float* __restrict__ ebhh,
    const float* __restrict__ Wdw,  const float* __restrict__ Wdb,
    const float* __restrict__ Udw,  const float* __restrict__ vdw,
    const float* __restrict__ wtw,  const float* __restrict__ wtb,
    const float* __restrict__ dWih, const float* __restrict__ dWhh,
    const float* __restrict__ dbih, const float* __restrict__ dbhh,
    const float* __restrict__ Wyw,  const float* __restrict__ Wyb,
    const float* __restrict__ vyw,  const float* __restrict__ vyb,
    float* __restrict__ out)
{
    extern __shared__ float S[];
    const int tid = threadIdx.x;   // 0..255
    const int b   = blockIdx.x;
    const int w   = tid >> 6;      // wave 0..3
    const int l   = tid & 63;      // lane

    // ===== init: stage Ue_w, ve, enc bias sums; zero both state buffers; img[0]
    for (int i = tid; i < 1024; i += 256) S[UE + i] = Uew[i];
    if (tid < 128) S[XVE + tid * 2 + 1] = vew[tid];
    S[EBIAS + tid] = ebih[tid] + ebhh[tid];
    S[HSB + tid] = 0.0f;
    if (tid < 32) S[HSB + 256 + tid] = 0.0f;
    if (tid < 81) S[IMG + tid] = Xh[((size_t)b * TSTEPS) * 81 + tid];
    __syncthreads();

    int pp = 0;

    // ===================== ENCODER (3 barriers/step) =====================
    for (int t = 0; t < TSTEPS; ++t) {
        // ---- I1: prefetch img[t+1] + (c) x + conv
        if (t + 1 < TSTEPS && tid < 81)
            S[IMG + ((t + 1) & 1) * 88 + tid] = Xh[((size_t)b * TSTEPS + t + 1) * 81 + tid];
        {   // x[j] = [h,s].We_w[j,:] + We_b[j]   (j = tid>>1, hk = k-half)
            int j = tid >> 1, hk = tid & 1;
            const float4* wr  = reinterpret_cast<const float4*>(Wew + j * 128 + hk * 64);
            const float4* hv0 = reinterpret_cast<const float4*>(S + HSB + pp * 144 + (2 * hk) * 36);
            const float4* hv1 = reinterpret_cast<const float4*>(S + HSB + pp * 144 + (2 * hk) * 36 + 36);
            float acc = 0.0f;
#pragma unroll
            for (int k = 0; k < 8; ++k) { float4 wv = wr[k],     xv = hv0[k]; FMA4(acc, wv, xv) }
#pragma unroll
            for (int k = 0; k < 8; ++k) { float4 wv = wr[8 + k], xv = hv1[k]; FMA4(acc, wv, xv) }
            acc += __shfl_xor(acc, 1);
            if (hk == 0) S[XVE + j * 2] = acc + Web[j];
        }
#pragma unroll
        for (int rep = 0; rep < 2; ++rep) {   // conv + relu -> CTLT[r][m]
            int idx = tid + rep * 256;
            int m = idx >> 3, r = idx & 7;
            const float* kw = convw + m * 18;
            const float* ib = S + IMG + (t & 1) * 88 + r * 9;
            float acc = convb[m];
#pragma unroll
            for (int wd = 0; wd < 9; ++wd) {
                acc = fmaf(ib[wd],     kw[wd],     acc);
                acc = fmaf(ib[9 + wd], kw[9 + wd], acc);
            }
            S[CTLT + r * 68 + m] = fmaxf(acc, 0.0f);
        }
        __syncthreads(); // A

        // ---- I2: e-partials (wave w covers 32 j; Ue rows broadcast)
        float cr[8];
#pragma unroll
        for (int c = 0; c < 8; ++c) cr[c] = S[CTLT + c * 68 + l];
        {
            float eacc = 0.0f;
#pragma unroll 4
            for (int jj = 0; jj < 32; ++jj) {
                int j = w * 32 + jj;
                float4 u0 = *reinterpret_cast<const float4*>(S + UE + j * 8);
                float4 u1 = *reinterpret_cast<const float4*>(S + UE + j * 8 + 4);
                float2 xv = *reinterpret_cast<const float2*>(S + XVE + j * 2);
                float s = xv.x;
                s = fmaf(u0.x, cr[0], s); s = fmaf(u0.y, cr[1], s);
                s = fmaf(u0.z, cr[2], s); s = fmaf(u0.w, cr[3], s);
                s = fmaf(u1.x, cr[4], s); s = fmaf(u1.y, cr[5], s);
                s = fmaf(u1.z, cr[6], s); s = fmaf(u1.w, cr[7], s);
                eacc = fmaf(ftanh(s), xv.y, eacc);
            }
            S[RED + w * 64 + l] = eacc;
        }
        __syncthreads(); // C

        // ---- I3: redundant softmax + win + preact + fused gates (ping-pong)
        float win[8];
        {
            float e = S[RED + l] + S[RED + 64 + l] + S[RED + 128 + l] + S[RED + 192 + l];
            float mx = e;
#pragma unroll
            for (int dd = 1; dd < 64; dd <<= 1) mx = fmaxf(mx, __shfl_xor(mx, dd));
            float ex = __expf(e - mx);
            float ssum = ex;
#pragma unroll
            for (int dd = 1; dd < 64; dd <<= 1) ssum += __shfl_xor(ssum, dd);
            float al = ex * rcpf(ssum);
#pragma unroll
            for (int c = 0; c < 8; ++c) win[c] = al * cr[c];
#pragma unroll
            for (int dd = 1; dd < 64; dd <<= 1) {
#pragma unroll
                for (int c = 0; c < 8; ++c) win[c] += __shfl_xor(win[c], dd);
            }
        }
        {   // preact row r = (q)*64 + a, q = tid&3, a = tid>>2 -> gate quad in lane quad
            int q = tid & 3, a = tid >> 2;
            int r = q * 64 + a;
            const float4* wih = reinterpret_cast<const float4*>(eWih + r * 8);
            float4 a0 = wih[0], a1 = wih[1];
            float acc = S[EBIAS + r];
            acc = fmaf(a0.x, win[0], acc); acc = fmaf(a0.y, win[1], acc);
            acc = fmaf(a0.z, win[2], acc); acc = fmaf(a0.w, win[3], acc);
            acc = fmaf(a1.x, win[4], acc); acc = fmaf(a1.y, win[5], acc);
            acc = fmaf(a1.z, win[6], acc); acc = fmaf(a1.w, win[7], acc);
            const float4* whh = reinterpret_cast<const float4*>(eWhh + r * 64);
            const float4* hv0 = reinterpret_cast<const float4*>(S + HSB + pp * 144);
            const float4* hv1 = reinterpret_cast<const float4*>(S + HSB + pp * 144 + 36);
#pragma unroll
            for (int k = 0; k < 8; ++k) { float4 wv = whh[k],     xv = hv0[k]; FMA4(acc, wv, xv) }
#pragma unroll
            for (int k = 0; k < 8; ++k) { float4 wv = whh[8 + k], xv = hv1[k]; FMA4(acc, wv, xv) }
            float actv = (q == 2) ? ftanh(acc) : fsigm(acc);
            float n1 = __shfl_xor(actv, 1);   // lane 4a: sigm(f)
            float n2 = __shfl_xor(actv, 2);   // lane 4a: tanh(g)
            float n3 = __shfl_xor(n1, 2);     // lane 4a: sigm(o)
            if (q == 0) {
                int ck = (a >> 5) * 36 + (a & 31);
                float s_old = S[HSB + pp * 144 + 72 + ck];
                float cst = n1 * s_old + actv * n2;
                float h = n3 * ftanh(cst);
                S[HSB + (pp ^ 1) * 144 + ck] = h;
                S[HSB + (pp ^ 1) * 144 + 72 + ck] = cst;
                S[ENC + t * 64 + a] = h;
            }
        }
        __syncthreads(); // E
        pp ^= 1;
    }

    // ===== decoder const staging + Uenc post-pass (one interval) =====
    if (tid < 65)  S[DC_WT + tid] = wtw[tid];
    S[DC_DWIH + tid] = dWih[tid];
    S[DC_DBIAS + tid] = dbih[tid] + dbhh[tid];
    if (tid < 64)  { S[DC_WDB + tid] = Wdb[tid]; S[DC_WYB + tid] = Wyb[tid]; S[DC_VY + tid] = vyw[tid]; }
    if (tid < 64)  S[XVE + tid * 2 + 1] = vdw[tid];
    if (tid < 128) S[DC_YH + tid] = yh[(size_t)b * TSTEPS + tid];
    S[HSB + tid] = 0.0f;
    if (tid < 32) S[HSB + 256 + tid] = 0.0f;
    if (tid == 0)  { S[DC_SC] = wtb[0]; S[DC_SC + 1] = vyb[0]; }
    {   // Uenc[j][tt] = sum_k Ud[j][k]*ENC[tt][k]; j = lane, ENC reads broadcast
        int e8 = w;   // quarter of tt space
#pragma unroll 1
        for (int q4 = 0; q4 < 4; ++q4) {
            float acc[8];
#pragma unroll
            for (int i = 0; i < 8; ++i) acc[i] = 0.0f;
#pragma unroll
            for (int kc = 0; kc < 4; ++kc) {
                const float4* ud = reinterpret_cast<const float4*>(Udw + l * 64 + kc * 16);
                float4 u0 = ud[0], u1 = ud[1], u2 = ud[2], u3 = ud[3];
#pragma unroll
                for (int i = 0; i < 8; ++i) {
                    const float4* er = reinterpret_cast<const float4*>(
                        S + ENC + (e8 * 32 + q4 * 8 + i) * 64 + kc * 16);
                    float4 e0 = er[0], e1 = er[1], e2 = er[2], e3 = er[3];
                    float a = acc[i];
                    FMA4(a, u0, e0) FMA4(a, u1, e1) FMA4(a, u2, e2) FMA4(a, u3, e3)
                    acc[i] = a;
                }
            }
#pragma unroll
            for (int i = 0; i < 8; ++i)
                S[UENC + l * 136 + e8 * 32 + q4 * 8 + i] = acc[i];
        }
    }
    __syncthreads();
    pp = 0;

    // ===================== DECODER (4 barriers/step) =====================
    float hacc;
    for (int t = 0; t < TSTEPS; ++t) {
        // ---- J1: x1 + hoisted hhdot (permuted row)
        {
            int j = tid >> 2, o = tid & 3;
            const float4* wd = reinterpret_cast<const float4*>(Wdw + j * 128 + o * 32);
            const float4* dv = reinterpret_cast<const float4*>(S + HSB + pp * 144 + o * 36);
            float acc = 0.0f;
#pragma unroll
            for (int k = 0; k < 8; ++k) { float4 wv = wd[k], xv = dv[k]; FMA4(acc, wv, xv) }
            acc += __shfl_xor(acc, 1);
            acc += __shfl_xor(acc, 2);
            if (o == 0) S[XVE + j * 2] = acc + S[DC_WDB + j];
        }
        {
            int r = (tid & 3) * 64 + (tid >> 2);
            const float4* whh = reinterpret_cast<const float4*>(dWhh + r * 64);
            const float4* dv0 = reinterpret_cast<const float4*>(S + HSB + pp * 144);
            const float4* dv1 = reinterpret_cast<const float4*>(S + HSB + pp * 144 + 36);
            hacc = 0.0f;
#pragma unroll
            for (int k = 0; k < 8; ++k) { float4 wv = whh[k],     xv = dv0[k]; FMA4(hacc, wv, xv) }
#pragma unroll
            for (int k = 0; k < 8; ++k) { float4 wv = whh[8 + k], xv = dv1[k]; FMA4(hacc, wv, xv) }
        }
        __syncthreads(); // A

        // ---- J2: l[tt] = sum_j tanh(x1[j] + Uenc[j][tt]) * vd[j]
        {
            int tt = tid >> 1, hk = tid & 1;
            float acc = 0.0f;
#pragma unroll 8
            for (int jj = 0; jj < 32; ++jj) {
                int j = hk * 32 + jj;
                float u = S[UENC + j * 136 + tt];
                float2 xv = *reinterpret_cast<const float2*>(S + XVE + j * 2);
                acc = fmaf(ftanh(xv.x + u), xv.y, acc);
            }
            acc += __shfl_xor(acc, 1);
            if (hk == 0) S[LBUF + tt] = acc;
        }
        __syncthreads(); // B

        // ---- J3: redundant softmax (own beta chunk, no barrier) + c_t partials
        {
            float v0 = S[LBUF + l], v1 = S[LBUF + 64 + l];
            float mx = fmaxf(v0, v1);
#pragma unroll
            for (int dd = 1; dd < 64; dd <<= 1) mx = fmaxf(mx, __shfl_xor(mx, dd));
            float e0 = __expf(v0 - mx), e1 = __expf(v1 - mx);
            float ssum = e0 + e1;
#pragma unroll
            for (int dd = 1; dd < 64; dd <<= 1) ssum += __shfl_xor(ssum, dd);
            float rr = rcpf(ssum);
            // wave w owns tt in [32w, 32w+32): w<2 -> e0 of lanes (w&1)*32..; else e1
            if ((l >> 5) == (w & 1)) {
                if (w < 2) S[BETA + l]      = e0 * rr;
                else       S[BETA + 64 + l] = e1 * rr;
            }
        }
        {   // c_t partials: own chunk only (written by own wave above)
            float acc = 0.0f;
#pragma unroll 8
            for (int i = 0; i < 32; ++i) {
                int ttk = w * 32 + i;
                acc = fmaf(S[BETA + ttk], S[ENC + ttk * 64 + l], acc);
            }
            S[GBUF + w * 64 + l] = acc;
        }
        __syncthreads(); // D

        // ---- J4: redundant c_t finish + y_tilda + preact + fused gates
        {
            float cv = S[GBUF + l] + S[GBUF + 64 + l] + S[GBUF + 128 + l] + S[GBUF + 192 + l];
            if (t == TSTEPS - 1 && w == 0) S[CTV + l] = cv;
            float p = cv * S[DC_WT + l];
#pragma unroll
            for (int dd = 1; dd < 64; dd <<= 1) p += __shfl_xor(p, dd);
            float yt = p + S[DC_YH + t] * S[DC_WT + 64] + S[DC_SC];
            int q = tid & 3, a = tid >> 2;
            int r = q * 64 + a;
            float acc = hacc + fmaf(yt, S[DC_DWIH + r], S[DC_DBIAS + r]);
            float actv = (q == 2) ? ftanh(acc) : fsigm(acc);
            float n1 = __shfl_xor(actv, 1);
            float n2 = __shfl_xor(actv, 2);
            float n3 = __shfl_xor(n1, 2);
            if (q == 0) {
                int ck = (a >> 5) * 36 + (a & 31);
                float s_old = S[HSB + pp * 144 + 72 + ck];
                float cst = n1 * s_old + actv * n2;
                float dnew = n3 * ftanh(cst);
                S[HSB + (pp ^ 1) * 144 + ck] = dnew;
                S[HSB + (pp ^ 1) * 144 + 72 + ck] = cst;
            }
        }
        __syncthreads(); // G
        pp ^= 1;
    }

    // ===================== HEAD =====================
    {
        int p = tid >> 2, o = tid & 3;
        const float4* wy = reinterpret_cast<const float4*>(Wyw + p * 128 + o * 32);
        const float4* sv = reinterpret_cast<const float4*>(
            (o < 2) ? (S + HSB + pp * 144 + o * 36) : (S + CTV + (o - 2) * 32));
        float acc = 0.0f;
#pragma unroll
        for (int k = 0; k < 8; ++k) { float4 wv = wy[k], xv = sv[k]; FMA4(acc, wv, xv) }
        acc += __shfl_xor(acc, 1);
        acc += __shfl_xor(acc, 2);
        if (o == 0) S[TYP + p] = acc + S[DC_WYB + p];
    }
    __syncthreads();
    if (tid < 64) {
        float v = S[TYP + tid] * S[DC_VY + tid];
#pragma unroll
        for (int dd = 1; dd < 64; dd <<= 1) v += __shfl_xor(v, dd);
        if (tid == 0) out[b] = v + S[DC_SC + 1];
    }
}

extern "C" void kernel_launch(void* const* d_in, const int* in_sizes, int n_in,
                              void* d_out, int out_size, void* d_ws, size_t ws_size,
                              hipStream_t stream) {
    const float* A[26];
    for (int i = 0; i < 26; ++i) A[i] = (const float*)d_in[i];
    (void)in_sizes; (void)n_in; (void)d_ws; (void)ws_size; (void)out_size;

    (void)hipFuncSetAttribute(reinterpret_cast<const void*>(dstp_kernel),
                              hipFuncAttributeMaxDynamicSharedMemorySize,
                              SMEMF * 4);

    dstp_kernel<<<dim3(512), dim3(256), SMEMF * 4, stream>>>(
        A[0], A[1], A[2], A[3], A[4], A[5], A[6], A[7], A[8], A[9],
        A[10], A[11], A[12], A[13], A[14], A[15], A[16], A[17], A[18], A[19],
        A[20], A[21], A[22], A[23], A[24], A[25], (float*)d_out);
}

// Round 11
// 1283.677 us; speedup vs baseline: 2.4263x; 2.4263x over previous
//
#include <hip/hip_runtime.h>

// DSTP-RNN fused forward v8: v7 structure with the correct __launch_bounds__(256,2)
// (v7's (256,4) forced VGPR=64 -> scratch spill -> 3.9GB HBM; rounds 2/4 prove
// (._,2) -> 128 VGPR, no spill, 2 WG/CU). 256-thread WG, one batch element per WG,
// 512 WGs. Barriers: 3/enc step, 4/dec step; fused in-register gates; ping-pong state.

#define TSTEPS 128

// LDS float offsets (total 20080 floats = 80320 B; 2 WG/CU: 160640 <= 163840)
#define ENC    0        // [128][64] encoded h
#define UENC   8192     // [64][136] Uenc transposed (2-way reads, ~free)
#define UE     16896    // 1024: Ue_w (encoder) ; decoder const pool overlays
#define EBIAS  17920    // 256: enc bias sums (ebih+ebhh), permuted-row indexed
#define CTLT   18176    // [8][68] conv tile (enc) ; DC_YH (dec, 128) overlays
#define XVE    18720    // [128][2] (x_j, ve_j) / (x1_j, vd_j)
#define HSB    18976    // [2][144]: ping-pong state, 4 chunks of 32 @ stride 36
#define GBUF   19264    // 256: dec c_t partials
#define RED    19520    // 256: enc e-partials ; dec BETA(128)+CTV(64)+TYP(64)
#define IMG    19776    // [2][88]: double-buffered 9x9 image
#define LBUF   19952    // 128: dec l
#define SMEMF  20080

// decoder const overlays (UE region, loaded after encoder)
#define DC_WT    (UE + 64)    // 65
#define DC_DWIH  (UE + 192)   // 256
#define DC_DBIAS (UE + 448)   // 256
#define DC_WDB   (UE + 704)   // 64
#define DC_WYB   (UE + 768)   // 64
#define DC_VY    (UE + 832)   // 64
#define DC_SC    (UE + 896)   // wtb, vyb
#define DC_YH    CTLT
#define BETA     RED          // 128 (dec)
#define CTV      (RED + 128)  // 64 (written only at t==127)
#define TYP      (RED + 192)  // 64 (head)

__device__ __forceinline__ float rcpf(float x) { return __builtin_amdgcn_rcpf(x); }
__device__ __forceinline__ float fsigm(float x) { return rcpf(1.0f + __expf(-x)); }
__device__ __forceinline__ float ftanh(float x) { return 1.0f - 2.0f * rcpf(1.0f + __expf(2.0f * x)); }

#define FMA4(d_, p_, q_) \
    d_ = fmaf((p_).x, (q_).x, d_); d_ = fmaf((p_).y, (q_).y, d_); \
    d_ = fmaf((p_).z, (q_).z, d_); d_ = fmaf((p_).w, (q_).w, d_);

__global__ __launch_bounds__(256, 2) void dstp_kernel(
    const float* __restrict__ Xh,   const float* __restrict__ yh,
    const float* __restrict__ convw,const float* __restrict__ convb,
    const float* __restrict__ Wew,  const float* __restrict__ Web,
    const float* __restrict__ Uew,  const float* __restrict__ vew,
    const float* __restrict__ eWih, const float* __restrict__ eWhh,
    const float* __restrict__ ebih, const float* __restrict__ ebhh,
    const float* __restrict__ Wdw,  const float* __restrict__ Wdb,
    const float* __restrict__ Udw,  const float* __restrict__ vdw,
    const float* __restrict__ wtw,  const float* __restrict__ wtb,
    const float* __restrict__ dWih, const float* __restrict__ dWhh,
    const float* __restrict__ dbih, const float* __restrict__ dbhh,
    const float* __restrict__ Wyw,  const float* __restrict__ Wyb,
    const float* __restrict__ vyw,  const float* __restrict__ vyb,
    float* __restrict__ out)
{
    extern __shared__ float S[];
    const int tid = threadIdx.x;   // 0..255
    const int b   = blockIdx.x;
    const int w   = tid >> 6;      // wave 0..3
    const int l   = tid & 63;      // lane

    // ===== init: stage Ue_w, ve, enc bias sums; zero both state buffers; img[0]
    for (int i = tid; i < 1024; i += 256) S[UE + i] = Uew[i];
    if (tid < 128) S[XVE + tid * 2 + 1] = vew[tid];
    S[EBIAS + tid] = ebih[tid] + ebhh[tid];
    S[HSB + tid] = 0.0f;
    if (tid < 32) S[HSB + 256 + tid] = 0.0f;
    if (tid < 81) S[IMG + tid] = Xh[((size_t)b * TSTEPS) * 81 + tid];
    __syncthreads();

    int pp = 0;

    // ===================== ENCODER (3 barriers/step) =====================
    for (int t = 0; t < TSTEPS; ++t) {
        // ---- I1: prefetch img[t+1] + (c) x + conv
        if (t + 1 < TSTEPS && tid < 81)
            S[IMG + ((t + 1) & 1) * 88 + tid] = Xh[((size_t)b * TSTEPS + t + 1) * 81 + tid];
        {   // x[j] = [h,s].We_w[j,:] + We_b[j]   (j = tid>>1, hk = k-half)
            int j = tid >> 1, hk = tid & 1;
            const float4* wr  = reinterpret_cast<const float4*>(Wew + j * 128 + hk * 64);
            const float4* hv0 = reinterpret_cast<const float4*>(S + HSB + pp * 144 + (2 * hk) * 36);
            const float4* hv1 = reinterpret_cast<const float4*>(S + HSB + pp * 144 + (2 * hk) * 36 + 36);
            float acc = 0.0f;
#pragma unroll
            for (int k = 0; k < 8; ++k) { float4 wv = wr[k],     xv = hv0[k]; FMA4(acc, wv, xv) }
#pragma unroll
            for (int k = 0; k < 8; ++k) { float4 wv = wr[8 + k], xv = hv1[k]; FMA4(acc, wv, xv) }
            acc += __shfl_xor(acc, 1);
            if (hk == 0) S[XVE + j * 2] = acc + Web[j];
        }
#pragma unroll
        for (int rep = 0; rep < 2; ++rep) {   // conv + relu -> CTLT[r][m]
            int idx = tid + rep * 256;
            int m = idx >> 3, r = idx & 7;
            const float* kw = convw + m * 18;
            const float* ib = S + IMG + (t & 1) * 88 + r * 9;
            float acc = convb[m];
#pragma unroll
            for (int wd = 0; wd < 9; ++wd) {
                acc = fmaf(ib[wd],     kw[wd],     acc);
                acc = fmaf(ib[9 + wd], kw[9 + wd], acc);
            }
            S[CTLT + r * 68 + m] = fmaxf(acc, 0.0f);
        }
        __syncthreads(); // A

        // ---- I2: e-partials (wave w covers 32 j; Ue rows broadcast)
        float cr[8];
#pragma unroll
        for (int c = 0; c < 8; ++c) cr[c] = S[CTLT + c * 68 + l];
        {
            float eacc = 0.0f;
#pragma unroll 4
            for (int jj = 0; jj < 32; ++jj) {
                int j = w * 32 + jj;
                float4 u0 = *reinterpret_cast<const float4*>(S + UE + j * 8);
                float4 u1 = *reinterpret_cast<const float4*>(S + UE + j * 8 + 4);
                float2 xv = *reinterpret_cast<const float2*>(S + XVE + j * 2);
                float s = xv.x;
                s = fmaf(u0.x, cr[0], s); s = fmaf(u0.y, cr[1], s);
                s = fmaf(u0.z, cr[2], s); s = fmaf(u0.w, cr[3], s);
                s = fmaf(u1.x, cr[4], s); s = fmaf(u1.y, cr[5], s);
                s = fmaf(u1.z, cr[6], s); s = fmaf(u1.w, cr[7], s);
                eacc = fmaf(ftanh(s), xv.y, eacc);
            }
            S[RED + w * 64 + l] = eacc;
        }
        __syncthreads(); // C

        // ---- I3: redundant softmax + win + preact + fused gates (ping-pong)
        float win[8];
        {
            float e = S[RED + l] + S[RED + 64 + l] + S[RED + 128 + l] + S[RED + 192 + l];
            float mx = e;
#pragma unroll
            for (int dd = 1; dd < 64; dd <<= 1) mx = fmaxf(mx, __shfl_xor(mx, dd));
            float ex = __expf(e - mx);
            float ssum = ex;
#pragma unroll
            for (int dd = 1; dd < 64; dd <<= 1) ssum += __shfl_xor(ssum, dd);
            float al = ex * rcpf(ssum);
#pragma unroll
            for (int c = 0; c < 8; ++c) win[c] = al * cr[c];
#pragma unroll
            for (int dd = 1; dd < 64; dd <<= 1) {
#pragma unroll
                for (int c = 0; c < 8; ++c) win[c] += __shfl_xor(win[c], dd);
            }
        }
        {   // preact row r = q*64 + a (q = tid&3, a = tid>>2) -> gate quad in lane quad
            int q = tid & 3, a = tid >> 2;
            int r = q * 64 + a;
            const float4* wih = reinterpret_cast<const float4*>(eWih + r * 8);
            float4 a0 = wih[0], a1 = wih[1];
            float acc = S[EBIAS + r];
            acc = fmaf(a0.x, win[0], acc); acc = fmaf(a0.y, win[1], acc);
            acc = fmaf(a0.z, win[2], acc); acc = fmaf(a0.w, win[3], acc);
            acc = fmaf(a1.x, win[4], acc); acc = fmaf(a1.y, win[5], acc);
            acc = fmaf(a1.z, win[6], acc); acc = fmaf(a1.w, win[7], acc);
            const float4* whh = reinterpret_cast<const float4*>(eWhh + r * 64);
            const float4* hv0 = reinterpret_cast<const float4*>(S + HSB + pp * 144);
            const float4* hv1 = reinterpret_cast<const float4*>(S + HSB + pp * 144 + 36);
#pragma unroll
            for (int k = 0; k < 8; ++k) { float4 wv = whh[k],     xv = hv0[k]; FMA4(acc, wv, xv) }
#pragma unroll
            for (int k = 0; k < 8; ++k) { float4 wv = whh[8 + k], xv = hv1[k]; FMA4(acc, wv, xv) }
            float actv = (q == 2) ? ftanh(acc) : fsigm(acc);
            float n1 = __shfl_xor(actv, 1);   // lane 4a: sigm(f)
            float n2 = __shfl_xor(actv, 2);   // lane 4a: tanh(g)
            float n3 = __shfl_xor(n1, 2);     // lane 4a: sigm(o)
            if (q == 0) {
                int ck = (a >> 5) * 36 + (a & 31);
                float s_old = S[HSB + pp * 144 + 72 + ck];
                float cst = n1 * s_old + actv * n2;
                float h = n3 * ftanh(cst);
                S[HSB + (pp ^ 1) * 144 + ck] = h;
                S[HSB + (pp ^ 1) * 144 + 72 + ck] = cst;
                S[ENC + t * 64 + a] = h;
            }
        }
        __syncthreads(); // E
        pp ^= 1;
    }

    // ===== decoder const staging + Uenc post-pass (one interval) =====
    if (tid < 65)  S[DC_WT + tid] = wtw[tid];
    S[DC_DWIH + tid] = dWih[tid];
    S[DC_DBIAS + tid] = dbih[tid] + dbhh[tid];
    if (tid < 64)  { S[DC_WDB + tid] = Wdb[tid]; S[DC_WYB + tid] = Wyb[tid]; S[DC_VY + tid] = vyw[tid]; }
    if (tid < 64)  S[XVE + tid * 2 + 1] = vdw[tid];
    if (tid < 128) S[DC_YH + tid] = yh[(size_t)b * TSTEPS + tid];
    S[HSB + tid] = 0.0f;
    if (tid < 32) S[HSB + 256 + tid] = 0.0f;
    if (tid == 0)  { S[DC_SC] = wtb[0]; S[DC_SC + 1] = vyb[0]; }
    {   // Uenc[j][tt] = sum_k Ud[j][k]*ENC[tt][k]; j = lane, ENC reads broadcast
        int e8 = w;   // quarter of tt space
#pragma unroll 1
        for (int q4 = 0; q4 < 4; ++q4) {
            float acc[8];
#pragma unroll
            for (int i = 0; i < 8; ++i) acc[i] = 0.0f;
#pragma unroll
            for (int kc = 0; kc < 4; ++kc) {
                const float4* ud = reinterpret_cast<const float4*>(Udw + l * 64 + kc * 16);
                float4 u0 = ud[0], u1 = ud[1], u2 = ud[2], u3 = ud[3];
#pragma unroll
                for (int i = 0; i < 8; ++i) {
                    const float4* er = reinterpret_cast<const float4*>(
                        S + ENC + (e8 * 32 + q4 * 8 + i) * 64 + kc * 16);
                    float4 e0 = er[0], e1 = er[1], e2 = er[2], e3 = er[3];
                    float a = acc[i];
                    FMA4(a, u0, e0) FMA4(a, u1, e1) FMA4(a, u2, e2) FMA4(a, u3, e3)
                    acc[i] = a;
                }
            }
#pragma unroll
            for (int i = 0; i < 8; ++i)
                S[UENC + l * 136 + e8 * 32 + q4 * 8 + i] = acc[i];
        }
    }
    __syncthreads();
    pp = 0;

    // ===================== DECODER (4 barriers/step) =====================
    float hacc;
    for (int t = 0; t < TSTEPS; ++t) {
        // ---- J1: x1 + hoisted hhdot (permuted row)
        {
            int j = tid >> 2, o = tid & 3;
            const float4* wd = reinterpret_cast<const float4*>(Wdw + j * 128 + o * 32);
            const float4* dv = reinterpret_cast<const float4*>(S + HSB + pp * 144 + o * 36);
            float acc = 0.0f;
#pragma unroll
            for (int k = 0; k < 8; ++k) { float4 wv = wd[k], xv = dv[k]; FMA4(acc, wv, xv) }
            acc += __shfl_xor(acc, 1);
            acc += __shfl_xor(acc, 2);
            if (o == 0) S[XVE + j * 2] = acc + S[DC_WDB + j];
        }
        {
            int r = (tid & 3) * 64 + (tid >> 2);
            const float4* whh = reinterpret_cast<const float4*>(dWhh + r * 64);
            const float4* dv0 = reinterpret_cast<const float4*>(S + HSB + pp * 144);
            const float4* dv1 = reinterpret_cast<const float4*>(S + HSB + pp * 144 + 36);
            hacc = 0.0f;
#pragma unroll
            for (int k = 0; k < 8; ++k) { float4 wv = whh[k],     xv = dv0[k]; FMA4(hacc, wv, xv) }
#pragma unroll
            for (int k = 0; k < 8; ++k) { float4 wv = whh[8 + k], xv = dv1[k]; FMA4(hacc, wv, xv) }
        }
        __syncthreads(); // A

        // ---- J2: l[tt] = sum_j tanh(x1[j] + Uenc[j][tt]) * vd[j]
        {
            int tt = tid >> 1, hk = tid & 1;
            float acc = 0.0f;
#pragma unroll 8
            for (int jj = 0; jj < 32; ++jj) {
                int j = hk * 32 + jj;
                float u = S[UENC + j * 136 + tt];
                float2 xv = *reinterpret_cast<const float2*>(S + XVE + j * 2);
                acc = fmaf(ftanh(xv.x + u), xv.y, acc);
            }
            acc += __shfl_xor(acc, 1);
            if (hk == 0) S[LBUF + tt] = acc;
        }
        __syncthreads(); // B

        // ---- J3: redundant softmax (own beta chunk, no barrier) + c_t partials
        {
            float v0 = S[LBUF + l], v1 = S[LBUF + 64 + l];
            float mx = fmaxf(v0, v1);
#pragma unroll
            for (int dd = 1; dd < 64; dd <<= 1) mx = fmaxf(mx, __shfl_xor(mx, dd));
            float e0 = __expf(v0 - mx), e1 = __expf(v1 - mx);
            float ssum = e0 + e1;
#pragma unroll
            for (int dd = 1; dd < 64; dd <<= 1) ssum += __shfl_xor(ssum, dd);
            float rr = rcpf(ssum);
            // wave w owns tt in [32w, 32w+32): w<2 -> e0 of lanes (w&1)*32..; else e1
            if ((l >> 5) == (w & 1)) {
                if (w < 2) S[BETA + l]      = e0 * rr;
                else       S[BETA + 64 + l] = e1 * rr;
            }
        }
        {   // c_t partials: own chunk only (written by own wave above)
            float acc = 0.0f;
#pragma unroll 8
            for (int i = 0; i < 32; ++i) {
                int ttk = w * 32 + i;
                acc = fmaf(S[BETA + ttk], S[ENC + ttk * 64 + l], acc);
            }
            S[GBUF + w * 64 + l] = acc;
        }
        __syncthreads(); // D

        // ---- J4: redundant c_t finish + y_tilda + preact + fused gates
        {
            float cv = S[GBUF + l] + S[GBUF + 64 + l] + S[GBUF + 128 + l] + S[GBUF + 192 + l];
            if (t == TSTEPS - 1 && w == 0) S[CTV + l] = cv;
            float p = cv * S[DC_WT + l];
#pragma unroll
            for (int dd = 1; dd < 64; dd <<= 1) p += __shfl_xor(p, dd);
            float yt = p + S[DC_YH + t] * S[DC_WT + 64] + S[DC_SC];
            int q = tid & 3, a = tid >> 2;
            int r = q * 64 + a;
            float acc = hacc + fmaf(yt, S[DC_DWIH + r], S[DC_DBIAS + r]);
            float actv = (q == 2) ? ftanh(acc) : fsigm(acc);
            float n1 = __shfl_xor(actv, 1);
            float n2 = __shfl_xor(actv, 2);
            float n3 = __shfl_xor(n1, 2);
            if (q == 0) {
                int ck = (a >> 5) * 36 + (a & 31);
                float s_old = S[HSB + pp * 144 + 72 + ck];
                float cst = n1 * s_old + actv * n2;
                float dnew = n3 * ftanh(cst);
                S[HSB + (pp ^ 1) * 144 + ck] = dnew;
                S[HSB + (pp ^ 1) * 144 + 72 + ck] = cst;
            }
        }
        __syncthreads(); // G
        pp ^= 1;
    }

    // ===================== HEAD =====================
    {
        int p = tid >> 2, o = tid & 3;
        const float4* wy = reinterpret_cast<const float4*>(Wyw + p * 128 + o * 32);
        const float4* sv = reinterpret_cast<const float4*>(
            (o < 2) ? (S + HSB + pp * 144 + o * 36) : (S + CTV + (o - 2) * 32));
        float acc = 0.0f;
#pragma unroll
        for (int k = 0; k < 8; ++k) { float4 wv = wy[k], xv = sv[k]; FMA4(acc, wv, xv) }
        acc += __shfl_xor(acc, 1);
        acc += __shfl_xor(acc, 2);
        if (o == 0) S[TYP + p] = acc + S[DC_WYB + p];
    }
    __syncthreads();
    if (tid < 64) {
        float v = S[TYP + tid] * S[DC_VY + tid];
#pragma unroll
        for (int dd = 1; dd < 64; dd <<= 1) v += __shfl_xor(v, dd);
        if (tid == 0) out[b] = v + S[DC_SC + 1];
    }
}

extern "C" void kernel_launch(void* const* d_in, const int* in_sizes, int n_in,
                              void* d_out, int out_size, void* d_ws, size_t ws_size,
                              hipStream_t stream) {
    const float* A[26];
    for (int i = 0; i < 26; ++i) A[i] = (const float*)d_in[i];
    (void)in_sizes; (void)n_in; (void)d_ws; (void)ws_size; (void)out_size;

    (void)hipFuncSetAttribute(reinterpret_cast<const void*>(dstp_kernel),
                              hipFuncAttributeMaxDynamicSharedMemorySize,
                              SMEMF * 4);

    dstp_kernel<<<dim3(512), dim3(256), SMEMF * 4, stream>>>(
        A[0], A[1], A[2], A[3], A[4], A[5], A[6], A[7], A[8], A[9],
        A[10], A[11], A[12], A[13], A[14], A[15], A[16], A[17], A[18], A[19],
        A[20], A[21], A[22], A[23], A[24], A[25], (float*)d_out);
}